// Round 1
// baseline (3873.412 us; speedup 1.0000x reference)
//
#include <hip/hip_runtime.h>
#include <hip/hip_bf16.h>
#include <math.h>

#define N_ENT   40000
#define N_REL2  480
#define D       128
#define T_STEPS 8
#define E_EDGES 200000
#define SQC     0.1f                 // sqrt(C), C = 0.01
#define RRELU_SLOPE 0.22916666666666666f
#define EPS_    1e-6f

// ---------------------------------------------------------------------------
// rel_w[r][c] = sum_k emb_rel[r][k] * w_neigh[k][c]   (once per call)
// ---------------------------------------------------------------------------
__global__ void relw_kernel(const float* __restrict__ emb_rel,
                            const float* __restrict__ w_neigh,
                            float* __restrict__ rel_w) {
    int row = blockIdx.x;        // 0..479
    int col = threadIdx.x;       // 0..127
    float acc = 0.f;
    #pragma unroll 8
    for (int k = 0; k < D; ++k)
        acc = fmaf(emb_rel[row * D + k], w_neigh[k * D + col], acc);
    rel_w[row * D + col] = acc;
}

// ---------------------------------------------------------------------------
// logmap0: h_tan = artanh(min(sqc*||h||,1-1e-5)) * h / (sqc*||h||)
// one wave (64 lanes) per node, 2 floats per lane
// ---------------------------------------------------------------------------
__global__ __launch_bounds__(256) void logmap_kernel(const float* __restrict__ h,
                                                     float* __restrict__ h_tan) {
    int wid  = (blockIdx.x * blockDim.x + threadIdx.x) >> 6;   // node id
    int lane = threadIdx.x & 63;
    if (wid >= N_ENT) return;
    int base = wid * D + lane * 2;
    float2 hv = *reinterpret_cast<const float2*>(h + base);
    float ss = hv.x * hv.x + hv.y * hv.y;
    #pragma unroll
    for (int off = 32; off >= 1; off >>= 1) ss += __shfl_xor(ss, off, 64);
    float n = fmaxf(sqrtf(ss), EPS_);
    float t = fminf(SQC * n, 1.0f - 1e-5f);
    float scale = atanhf(t) / (SQC * n);
    float2 o; o.x = hv.x * scale; o.y = hv.y * scale;
    *reinterpret_cast<float2*>(h_tan + base) = o;
}

// ---------------------------------------------------------------------------
// Fused GEMM: O{n,l,g} = A @ W{n,l,g}; A=[N,128], W=[128,128].
// blockIdx.y selects which weight. 64-row tile, 256 threads, 4x8 micro-tile.
// ---------------------------------------------------------------------------
__global__ __launch_bounds__(256) void gemm3_kernel(
        const float* __restrict__ A,
        const float* __restrict__ Wn, const float* __restrict__ Wl, const float* __restrict__ Wg,
        float* __restrict__ On, float* __restrict__ Ol, float* __restrict__ Og) {
    const float* W; float* O;
    if (blockIdx.y == 0)      { W = Wn; O = On; }
    else if (blockIdx.y == 1) { W = Wl; O = Ol; }
    else                      { W = Wg; O = Og; }

    __shared__ float a_s[64][132];     // +4 pad: spreads rows across banks
    const int tid = threadIdx.x;
    const int rowBase = blockIdx.x * 64;

    // stage A tile: 64x128 floats = 256 threads x 8 float4
    #pragma unroll
    for (int j = 0; j < 8; ++j) {
        int flat = j * 1024 + tid * 4;
        int r = flat >> 7, c = flat & 127;
        float4 v = *reinterpret_cast<const float4*>(A + (rowBase + r) * D + c);
        *reinterpret_cast<float4*>(&a_s[r][c]) = v;
    }
    __syncthreads();

    const int tx = tid & 15, ty = tid >> 4;
    const int r0 = ty * 4, c0 = tx * 8;

    float acc[4][8];
    #pragma unroll
    for (int i = 0; i < 4; ++i)
        #pragma unroll
        for (int j = 0; j < 8; ++j) acc[i][j] = 0.f;

    for (int k = 0; k < D; k += 4) {
        float4 a[4];
        #pragma unroll
        for (int i = 0; i < 4; ++i)
            a[i] = *reinterpret_cast<const float4*>(&a_s[r0 + i][k]);
        #pragma unroll
        for (int kk = 0; kk < 4; ++kk) {
            float4 w0 = *reinterpret_cast<const float4*>(W + (k + kk) * D + c0);
            float4 w1 = *reinterpret_cast<const float4*>(W + (k + kk) * D + c0 + 4);
            #pragma unroll
            for (int i = 0; i < 4; ++i) {
                float av = (kk == 0) ? a[i].x : (kk == 1) ? a[i].y : (kk == 2) ? a[i].z : a[i].w;
                acc[i][0] = fmaf(av, w0.x, acc[i][0]);
                acc[i][1] = fmaf(av, w0.y, acc[i][1]);
                acc[i][2] = fmaf(av, w0.z, acc[i][2]);
                acc[i][3] = fmaf(av, w0.w, acc[i][3]);
                acc[i][4] = fmaf(av, w1.x, acc[i][4]);
                acc[i][5] = fmaf(av, w1.y, acc[i][5]);
                acc[i][6] = fmaf(av, w1.z, acc[i][6]);
                acc[i][7] = fmaf(av, w1.w, acc[i][7]);
            }
        }
    }

    #pragma unroll
    for (int i = 0; i < 4; ++i) {
        float* op = O + (rowBase + r0 + i) * D + c0;
        float4 o0 = {acc[i][0], acc[i][1], acc[i][2], acc[i][3]};
        float4 o1 = {acc[i][4], acc[i][5], acc[i][6], acc[i][7]};
        *reinterpret_cast<float4*>(op)     = o0;
        *reinterpret_cast<float4*>(op + 4) = o1;
    }
}

// ---------------------------------------------------------------------------
// Edge scatter: agg[d] += hw_neigh[s] + rel_w[r]; cnt[d] += 1
// 32 threads per edge, 4 floats per thread
// ---------------------------------------------------------------------------
__global__ __launch_bounds__(256) void edge_kernel(
        const int* __restrict__ src, const int* __restrict__ dst, const int* __restrict__ rel,
        const float* __restrict__ hw_neigh, const float* __restrict__ rel_w,
        float* __restrict__ agg, float* __restrict__ cnt) {
    int gtid = blockIdx.x * blockDim.x + threadIdx.x;
    int e  = gtid >> 5;
    if (e >= E_EDGES) return;
    int c4 = (gtid & 31) * 4;
    int s = src[e], d = dst[e], r = rel[e];
    float4 hv = *reinterpret_cast<const float4*>(hw_neigh + s * D + c4);
    float4 rv = *reinterpret_cast<const float4*>(rel_w + r * D + c4);
    float* ap = agg + d * D + c4;
    atomicAdd(ap + 0, hv.x + rv.x);
    atomicAdd(ap + 1, hv.y + rv.y);
    atomicAdd(ap + 2, hv.z + rv.z);
    atomicAdd(ap + 3, hv.w + rv.w);
    if ((gtid & 31) == 0) atomicAdd(cnt + d, 1.0f);
}

// ---------------------------------------------------------------------------
// Node update: mean, self-loop, rrelu, logmap0(expmap0(.)), gate, expmap0
// one wave per node, 2 floats per lane
// ---------------------------------------------------------------------------
__device__ __forceinline__ float wave_sum(float v) {
    #pragma unroll
    for (int off = 32; off >= 1; off >>= 1) v += __shfl_xor(v, off, 64);
    return v;
}

__global__ __launch_bounds__(256) void update_kernel(
        const float* __restrict__ h_tan, const float* __restrict__ agg,
        const float* __restrict__ cnt,  const float* __restrict__ hw_loop,
        const float* __restrict__ gate_pre, float* __restrict__ h_out) {
    int wid  = (blockIdx.x * blockDim.x + threadIdx.x) >> 6;
    int lane = threadIdx.x & 63;
    if (wid >= N_ENT) return;
    int base = wid * D + lane * 2;

    float2 ag = *reinterpret_cast<const float2*>(agg + base);
    float2 hl = *reinterpret_cast<const float2*>(hw_loop + base);
    float2 ht = *reinterpret_cast<const float2*>(h_tan + base);
    float2 gp = *reinterpret_cast<const float2*>(gate_pre + base);
    float inv = 1.0f / fmaxf(cnt[wid], 1.0f);

    float ox = fmaf(ag.x, inv, hl.x);
    float oy = fmaf(ag.y, inv, hl.y);
    ox = (ox >= 0.f) ? ox : RRELU_SLOPE * ox;   // rrelu (eval mode)
    oy = (oy >= 0.f) ? oy : RRELU_SLOPE * oy;

    // expmap0(out_tan)
    float nu = fmaxf(sqrtf(wave_sum(ox * ox + oy * oy)), EPS_);
    float su = tanhf(SQC * nu) / (SQC * nu);
    float xx = ox * su, xy = oy * su;

    // logmap0(x)
    float nx = fmaxf(sqrtf(wave_sum(xx * xx + xy * xy)), EPS_);
    float tt = fminf(SQC * nx, 1.0f - 1e-5f);
    float sl = atanhf(tt) / (SQC * nx);
    float hnx = xx * sl, hny = xy * sl;

    // gate = sigmoid(gate_pre)
    float gx = 1.0f / (1.0f + expf(-gp.x));
    float gy = 1.0f / (1.0f + expf(-gp.y));
    float mx = fmaf(gx, hnx - ht.x, ht.x);   // gx*hnx + (1-gx)*ht.x
    float my = fmaf(gy, hny - ht.y, ht.y);

    // expmap0(mixed)
    float nm = fmaxf(sqrtf(wave_sum(mx * mx + my * my)), EPS_);
    float sm = tanhf(SQC * nm) / (SQC * nm);

    float2 o; o.x = mx * sm; o.y = my * sm;
    *reinterpret_cast<float2*>(h_out + base) = o;
}

// ---------------------------------------------------------------------------
extern "C" void kernel_launch(void* const* d_in, const int* in_sizes, int n_in,
                              void* d_out, int out_size, void* d_ws, size_t ws_size,
                              hipStream_t stream) {
    const int*   src  = (const int*)d_in[0];   // [T,E]
    const int*   dst  = (const int*)d_in[1];   // [T,E]
    const int*   rel  = (const int*)d_in[2];   // [T,E]
    const float* dyn  = (const float*)d_in[3]; // [N,D]
    const float* erel = (const float*)d_in[4]; // [480,D]
    const float* wn   = (const float*)d_in[5]; // [D,D]
    const float* wl   = (const float*)d_in[6];
    const float* wg   = (const float*)d_in[7];
    float* h = (float*)d_out;                  // [N,D], updated in place

    const size_t ND = (size_t)N_ENT * D;
    float* ws       = (float*)d_ws;
    float* h_tan    = ws;
    float* hw_neigh = h_tan    + ND;
    float* hw_loop  = hw_neigh + ND;
    float* gate_pre = hw_loop  + ND;
    float* agg      = gate_pre + ND;
    float* cntv     = agg      + ND;
    float* rel_w    = cntv     + N_ENT;

    // h0 = dynamic_emb
    hipMemcpyAsync(h, dyn, ND * sizeof(float), hipMemcpyDeviceToDevice, stream);
    // rel_w = emb_rel @ w_neigh (loop-invariant)
    relw_kernel<<<N_REL2, D, 0, stream>>>(erel, wn, rel_w);

    const int nodeBlocks = (N_ENT * 64 + 255) / 256;          // 10000
    const int edgeBlocks = (E_EDGES * 32 + 255) / 256;        // 25000

    for (int t = 0; t < T_STEPS; ++t) {
        logmap_kernel<<<nodeBlocks, 256, 0, stream>>>(h, h_tan);
        gemm3_kernel<<<dim3(N_ENT / 64, 3), 256, 0, stream>>>(
            h_tan, wn, wl, wg, hw_neigh, hw_loop, gate_pre);
        hipMemsetAsync(agg, 0, ND * sizeof(float), stream);
        hipMemsetAsync(cntv, 0, N_ENT * sizeof(float), stream);
        edge_kernel<<<edgeBlocks, 256, 0, stream>>>(
            src + (size_t)t * E_EDGES, dst + (size_t)t * E_EDGES, rel + (size_t)t * E_EDGES,
            hw_neigh, rel_w, agg, cntv);
        update_kernel<<<nodeBlocks, 256, 0, stream>>>(
            h_tan, agg, cntv, hw_loop, gate_pre, h);
    }
}

// Round 2
// 1289.499 us; speedup vs baseline: 3.0038x; 3.0038x over previous
//
#include <hip/hip_runtime.h>
#include <hip/hip_bf16.h>
#include <math.h>

#define N_ENT   40000
#define N_REL2  480
#define D       128
#define T_STEPS 8
#define E_EDGES 200000
#define SQC     0.1f                 // sqrt(C), C = 0.01
#define RRELU_SLOPE 0.22916666666666666f
#define EPS_    1e-6f

#define NPAD    40960                // 40 blocks x 1024 (scan padding)

// ---------------------------------------------------------------------------
// rel_w[r][c] = sum_k emb_rel[r][k] * w_neigh[k][c]   (once per call)
// ---------------------------------------------------------------------------
__global__ void relw_kernel(const float* __restrict__ emb_rel,
                            const float* __restrict__ w_neigh,
                            float* __restrict__ rel_w) {
    int row = blockIdx.x;
    int col = threadIdx.x;
    float acc = 0.f;
    #pragma unroll 8
    for (int k = 0; k < D; ++k)
        acc = fmaf(emb_rel[row * D + k], w_neigh[k * D + col], acc);
    rel_w[row * D + col] = acc;
}

// ---------------------------------------------------------------------------
// logmap0 (step 0 only): h_tan = artanh(min(sqc*||h||,1-1e-5)) * h/(sqc*||h||)
// ---------------------------------------------------------------------------
__global__ __launch_bounds__(256) void logmap_kernel(const float* __restrict__ h,
                                                     float* __restrict__ h_tan) {
    int wid  = (blockIdx.x * blockDim.x + threadIdx.x) >> 6;
    int lane = threadIdx.x & 63;
    if (wid >= N_ENT) return;
    int base = wid * D + lane * 2;
    float2 hv = *reinterpret_cast<const float2*>(h + base);
    float ss = hv.x * hv.x + hv.y * hv.y;
    #pragma unroll
    for (int off = 32; off >= 1; off >>= 1) ss += __shfl_xor(ss, off, 64);
    float n = fmaxf(sqrtf(ss), EPS_);
    float t = fminf(SQC * n, 1.0f - 1e-5f);
    float scale = atanhf(t) / (SQC * n);
    float2 o; o.x = hv.x * scale; o.y = hv.y * scale;
    *reinterpret_cast<float2*>(h_tan + base) = o;
}

// ---------------------------------------------------------------------------
// CSR build: histogram -> batched exclusive scan -> scatter (int atomics only)
// ---------------------------------------------------------------------------
__global__ __launch_bounds__(256) void hist_kernel(const int* __restrict__ dst,
                                                   int* __restrict__ hist) {
    int t = blockIdx.y;
    int e = blockIdx.x * blockDim.x + threadIdx.x;
    if (e >= E_EDGES) return;
    int d = dst[(size_t)t * E_EDGES + e];
    atomicAdd(&hist[t * N_ENT + d], 1);
}

// inclusive per-block scan of hist (1024-chunk), store chunk scans + block totals
__global__ __launch_bounds__(1024) void scanA_kernel(const int* __restrict__ hist,
                                                     int* __restrict__ scanned,
                                                     int* __restrict__ partial) {
    __shared__ int s[1024];
    int t = blockIdx.y, blk = blockIdx.x, tid = threadIdx.x;
    int idx = blk * 1024 + tid;
    int v = (idx < N_ENT) ? hist[t * N_ENT + idx] : 0;
    s[tid] = v; __syncthreads();
    #pragma unroll
    for (int off = 1; off < 1024; off <<= 1) {
        int x = (tid >= off) ? s[tid - off] : 0;
        __syncthreads();
        s[tid] += x;
        __syncthreads();
    }
    scanned[t * NPAD + idx] = s[tid];
    if (tid == 1023) partial[t * 40 + blk] = s[1023];
}

// exclusive scan of the 40 block totals per step
__global__ __launch_bounds__(64) void scanB_kernel(int* __restrict__ partial) {
    int t = blockIdx.x, tid = threadIdx.x;
    int orig = (tid < 40) ? partial[t * 40 + tid] : 0;
    int v = orig;
    #pragma unroll
    for (int off = 1; off < 64; off <<= 1) {
        int x = __shfl_up(v, off, 64);
        if (tid >= off) v += x;
    }
    if (tid < 40) partial[t * 40 + tid] = v - orig;   // exclusive
}

// row_ptr (exclusive CSR offsets) + cursor init
__global__ __launch_bounds__(1024) void scanC_kernel(const int* __restrict__ hist,
                                                     const int* __restrict__ scanned,
                                                     const int* __restrict__ partial,
                                                     int* __restrict__ row_ptr,
                                                     int* __restrict__ cursor) {
    int t = blockIdx.y, blk = blockIdx.x, tid = threadIdx.x;
    int idx = blk * 1024 + tid;
    if (idx >= N_ENT) return;
    int incl = scanned[t * NPAD + idx] + partial[t * 40 + blk];  // global inclusive
    row_ptr[t * (N_ENT + 1) + idx + 1] = incl;
    cursor[t * N_ENT + idx] = incl - hist[t * N_ENT + idx];      // exclusive
    if (idx == 0) row_ptr[t * (N_ENT + 1)] = 0;
}

__global__ __launch_bounds__(256) void scatter_kernel(const int* __restrict__ src,
                                                      const int* __restrict__ dst,
                                                      const int* __restrict__ rel,
                                                      int* __restrict__ cursor,
                                                      int2* __restrict__ sorted) {
    int t = blockIdx.y;
    int e = blockIdx.x * blockDim.x + threadIdx.x;
    if (e >= E_EDGES) return;
    size_t o = (size_t)t * E_EDGES + e;
    int d = dst[o];
    int pos = atomicAdd(&cursor[t * N_ENT + d], 1);
    sorted[(size_t)t * E_EDGES + pos] = make_int2(src[o], rel[o]);
}

// ---------------------------------------------------------------------------
// Fused GEMM: O{n,l,g} = A @ W{n,l,g}, A staged in LDS once, 3 weights looped
// ---------------------------------------------------------------------------
__global__ __launch_bounds__(256) void gemm3_kernel(
        const float* __restrict__ A,
        const float* __restrict__ Wn, const float* __restrict__ Wl, const float* __restrict__ Wg,
        float* __restrict__ On, float* __restrict__ Ol, float* __restrict__ Og) {
    __shared__ float a_s[64][132];
    const int tid = threadIdx.x;
    const int rowBase = blockIdx.x * 64;

    #pragma unroll
    for (int j = 0; j < 8; ++j) {
        int flat = j * 1024 + tid * 4;
        int r = flat >> 7, c = flat & 127;
        float4 v = *reinterpret_cast<const float4*>(A + (rowBase + r) * D + c);
        *reinterpret_cast<float4*>(&a_s[r][c]) = v;
    }
    __syncthreads();

    const int tx = tid & 15, ty = tid >> 4;
    const int r0 = ty * 4, c0 = tx * 8;

    for (int w = 0; w < 3; ++w) {
        const float* W = (w == 0) ? Wn : (w == 1) ? Wl : Wg;
        float*       O = (w == 0) ? On : (w == 1) ? Ol : Og;

        float acc[4][8];
        #pragma unroll
        for (int i = 0; i < 4; ++i)
            #pragma unroll
            for (int j = 0; j < 8; ++j) acc[i][j] = 0.f;

        for (int k = 0; k < D; k += 4) {
            float4 a[4];
            #pragma unroll
            for (int i = 0; i < 4; ++i)
                a[i] = *reinterpret_cast<const float4*>(&a_s[r0 + i][k]);
            #pragma unroll
            for (int kk = 0; kk < 4; ++kk) {
                float4 w0 = *reinterpret_cast<const float4*>(W + (k + kk) * D + c0);
                float4 w1 = *reinterpret_cast<const float4*>(W + (k + kk) * D + c0 + 4);
                #pragma unroll
                for (int i = 0; i < 4; ++i) {
                    float av = (kk == 0) ? a[i].x : (kk == 1) ? a[i].y : (kk == 2) ? a[i].z : a[i].w;
                    acc[i][0] = fmaf(av, w0.x, acc[i][0]);
                    acc[i][1] = fmaf(av, w0.y, acc[i][1]);
                    acc[i][2] = fmaf(av, w0.z, acc[i][2]);
                    acc[i][3] = fmaf(av, w0.w, acc[i][3]);
                    acc[i][4] = fmaf(av, w1.x, acc[i][4]);
                    acc[i][5] = fmaf(av, w1.y, acc[i][5]);
                    acc[i][6] = fmaf(av, w1.z, acc[i][6]);
                    acc[i][7] = fmaf(av, w1.w, acc[i][7]);
                }
            }
        }

        #pragma unroll
        for (int i = 0; i < 4; ++i) {
            float* op = O + (rowBase + r0 + i) * D + c0;
            float4 o0 = {acc[i][0], acc[i][1], acc[i][2], acc[i][3]};
            float4 o1 = {acc[i][4], acc[i][5], acc[i][6], acc[i][7]};
            *reinterpret_cast<float4*>(op)     = o0;
            *reinterpret_cast<float4*>(op + 4) = o1;
        }
    }
}

// ---------------------------------------------------------------------------
// Fused gather + update: CSR gather-mean, self-loop, rrelu,
// logmap0(expmap0(.)), gate mix, expmap0 -> h, logmap0 -> h_tan (next step)
// ---------------------------------------------------------------------------
__device__ __forceinline__ float wave_sum(float v) {
    #pragma unroll
    for (int off = 32; off >= 1; off >>= 1) v += __shfl_xor(v, off, 64);
    return v;
}

__global__ __launch_bounds__(256) void gather_update_kernel(
        float* __restrict__ h_tan,          // in: current, out: next (in-place, own row only)
        const float* __restrict__ hw_neigh, const float* __restrict__ hw_loop,
        const float* __restrict__ gate_pre, const float* __restrict__ rel_w,
        const int* __restrict__ row_ptr, const int2* __restrict__ sorted,
        float* __restrict__ h_out, int write_h) {
    int wid  = (blockIdx.x * blockDim.x + threadIdx.x) >> 6;
    int lane = threadIdx.x & 63;
    if (wid >= N_ENT) return;
    int base = wid * D + lane * 2;

    int beg = row_ptr[wid], end = row_ptr[wid + 1];
    float ax = 0.f, ay = 0.f;
    for (int e = beg; e < end; ++e) {
        int2 sr = sorted[e];                                    // wave-broadcast load
        float2 hv = *reinterpret_cast<const float2*>(hw_neigh + sr.x * D + lane * 2);
        float2 rv = *reinterpret_cast<const float2*>(rel_w    + sr.y * D + lane * 2);
        ax += hv.x + rv.x;
        ay += hv.y + rv.y;
    }
    float inv = 1.0f / fmaxf((float)(end - beg), 1.0f);

    float2 hl = *reinterpret_cast<const float2*>(hw_loop  + base);
    float2 ht = *reinterpret_cast<const float2*>(h_tan    + base);
    float2 gp = *reinterpret_cast<const float2*>(gate_pre + base);

    float ox = fmaf(ax, inv, hl.x);
    float oy = fmaf(ay, inv, hl.y);
    ox = (ox >= 0.f) ? ox : RRELU_SLOPE * ox;
    oy = (oy >= 0.f) ? oy : RRELU_SLOPE * oy;

    // expmap0(out_tan)
    float nu = fmaxf(sqrtf(wave_sum(ox * ox + oy * oy)), EPS_);
    float su = tanhf(SQC * nu) / (SQC * nu);
    float xx = ox * su, xy = oy * su;

    // logmap0(x)
    float nx = fmaxf(sqrtf(wave_sum(xx * xx + xy * xy)), EPS_);
    float tt = fminf(SQC * nx, 1.0f - 1e-5f);
    float sl = atanhf(tt) / (SQC * nx);
    float hnx = xx * sl, hny = xy * sl;

    // gate mix
    float gx = 1.0f / (1.0f + expf(-gp.x));
    float gy = 1.0f / (1.0f + expf(-gp.y));
    float mx = fmaf(gx, hnx - ht.x, ht.x);
    float my = fmaf(gy, hny - ht.y, ht.y);

    // h = expmap0(mixed)
    float nm = fmaxf(sqrtf(wave_sum(mx * mx + my * my)), EPS_);
    float sm = tanhf(SQC * nm) / (SQC * nm);
    float hx = mx * sm, hy = my * sm;

    if (write_h) {
        float2 o; o.x = hx; o.y = hy;
        *reinterpret_cast<float2*>(h_out + base) = o;
    }

    // h_tan(next) = logmap0(h)  — exact reference chain
    float nh = fmaxf(sqrtf(wave_sum(hx * hx + hy * hy)), EPS_);
    float th = fminf(SQC * nh, 1.0f - 1e-5f);
    float slh = atanhf(th) / (SQC * nh);
    float2 o2; o2.x = hx * slh; o2.y = hy * slh;
    *reinterpret_cast<float2*>(h_tan + base) = o2;
}

// ---------------------------------------------------------------------------
extern "C" void kernel_launch(void* const* d_in, const int* in_sizes, int n_in,
                              void* d_out, int out_size, void* d_ws, size_t ws_size,
                              hipStream_t stream) {
    const int*   src  = (const int*)d_in[0];   // [T,E]
    const int*   dst  = (const int*)d_in[1];   // [T,E]
    const int*   rel  = (const int*)d_in[2];   // [T,E]
    const float* dyn  = (const float*)d_in[3]; // [N,D]
    const float* erel = (const float*)d_in[4]; // [480,D]
    const float* wn   = (const float*)d_in[5];
    const float* wl   = (const float*)d_in[6];
    const float* wg   = (const float*)d_in[7];
    float* h = (float*)d_out;

    const size_t ND = (size_t)N_ENT * D;
    float* f        = (float*)d_ws;
    float* h_tan    = f;
    float* hw_neigh = h_tan    + ND;
    float* hw_loop  = hw_neigh + ND;
    float* gate_pre = hw_loop  + ND;
    float* rel_w    = gate_pre + ND;                 // 480*128
    int2*  sorted   = (int2*)(rel_w + N_REL2 * D);   // 8B-aligned (offset divisible by 8)
    int*   hist     = (int*)(sorted + (size_t)T_STEPS * E_EDGES);
    int*   scanned  = hist    + T_STEPS * N_ENT;
    int*   partial  = scanned + T_STEPS * NPAD;
    int*   row_ptr  = partial + T_STEPS * 40;
    int*   cursor   = row_ptr + T_STEPS * (N_ENT + 1);

    const int nodeBlocks = (N_ENT * 64 + 255) / 256;           // 10000
    const int edgeB      = (E_EDGES + 255) / 256;              // 782

    // --- CSR build for all 8 steps (int atomics only) ---
    hipMemsetAsync(hist, 0, (size_t)T_STEPS * N_ENT * sizeof(int), stream);
    hist_kernel<<<dim3(edgeB, T_STEPS), 256, 0, stream>>>(dst, hist);
    scanA_kernel<<<dim3(40, T_STEPS), 1024, 0, stream>>>(hist, scanned, partial);
    scanB_kernel<<<T_STEPS, 64, 0, stream>>>(partial);
    scanC_kernel<<<dim3(40, T_STEPS), 1024, 0, stream>>>(hist, scanned, partial, row_ptr, cursor);
    scatter_kernel<<<dim3(edgeB, T_STEPS), 256, 0, stream>>>(src, dst, rel, cursor, sorted);

    // --- loop-invariant precompute ---
    relw_kernel<<<N_REL2, D, 0, stream>>>(erel, wn, rel_w);
    logmap_kernel<<<nodeBlocks, 256, 0, stream>>>(dyn, h_tan);

    for (int t = 0; t < T_STEPS; ++t) {
        gemm3_kernel<<<N_ENT / 64, 256, 0, stream>>>(
            h_tan, wn, wl, wg, hw_neigh, hw_loop, gate_pre);
        gather_update_kernel<<<nodeBlocks, 256, 0, stream>>>(
            h_tan, hw_neigh, hw_loop, gate_pre, rel_w,
            row_ptr + t * (N_ENT + 1), sorted + (size_t)t * E_EDGES,
            h, (t == T_STEPS - 1) ? 1 : 0);
    }
}

// Round 4
// 832.376 us; speedup vs baseline: 4.6534x; 1.5492x over previous
//
#include <hip/hip_runtime.h>
#include <hip/hip_bf16.h>
#include <math.h>

#define N_ENT   40000
#define N_REL2  480
#define D       128
#define T_STEPS 8
#define E_EDGES 200000
#define SQC     0.1f                 // sqrt(C), C = 0.01
#define RRELU_SLOPE 0.22916666666666666f
#define EPS_    1e-6f
#define NPAD    40960                // 40 blocks x 1024 (scan padding)

typedef _Float16 f16;
typedef _Float16 f16x8 __attribute__((ext_vector_type(8)));
typedef _Float16 f16x4 __attribute__((ext_vector_type(4)));
typedef _Float16 f16x2 __attribute__((ext_vector_type(2)));
typedef float    f32x4 __attribute__((ext_vector_type(4)));

// ---------------------------------------------------------------------------
// rel_w16[r][c] = (f16) sum_k emb_rel[r][k] * w_neigh[k][c]
// ---------------------------------------------------------------------------
__global__ void relw_kernel(const float* __restrict__ emb_rel,
                            const float* __restrict__ w_neigh,
                            f16* __restrict__ rel_w16) {
    int row = blockIdx.x, col = threadIdx.x;
    float acc = 0.f;
    #pragma unroll 8
    for (int k = 0; k < D; ++k)
        acc = fmaf(emb_rel[row * D + k], w_neigh[k * D + col], acc);
    rel_w16[row * D + col] = (f16)acc;
}

// ---------------------------------------------------------------------------
// Wpack: fragment-layout fp16 pack of {wn,wl,wg}.
// pack[(((g*8+nt)*4+ks)*64 + lane)*8 + j] = Wg[ks*32+(lane>>4)*8+j][nt*16+(lane&15)]
// ---------------------------------------------------------------------------
__global__ __launch_bounds__(256) void cvtw_kernel(const float* __restrict__ wn,
                                                   const float* __restrict__ wl,
                                                   const float* __restrict__ wg,
                                                   f16* __restrict__ wpack) {
    int idx = blockIdx.x * blockDim.x + threadIdx.x;   // 0 .. 49151
    int j    = idx & 7;
    int lane = (idx >> 3) & 63;
    int ks   = (idx >> 9) & 3;
    int nt   = (idx >> 11) & 7;
    int g    = idx >> 14;
    const float* W = (g == 0) ? wn : (g == 1) ? wl : wg;
    int k = ks * 32 + (lane >> 4) * 8 + j;
    int n = nt * 16 + (lane & 15);
    wpack[idx] = (f16)W[k * D + n];
}

// ---------------------------------------------------------------------------
// logmap0 of initial h: h_tan (fp32) + h_tan16 (fp16)
// ---------------------------------------------------------------------------
__global__ __launch_bounds__(256) void logmap_kernel(const float* __restrict__ h,
                                                     float* __restrict__ h_tan,
                                                     f16* __restrict__ h_tan16) {
    int wid  = (blockIdx.x * blockDim.x + threadIdx.x) >> 6;
    int lane = threadIdx.x & 63;
    if (wid >= N_ENT) return;
    int base = wid * D + lane * 2;
    float2 hv = *reinterpret_cast<const float2*>(h + base);
    float ss = hv.x * hv.x + hv.y * hv.y;
    #pragma unroll
    for (int off = 32; off >= 1; off >>= 1) ss += __shfl_xor(ss, off, 64);
    float n = fmaxf(sqrtf(ss), EPS_);
    float t = fminf(SQC * n, 1.0f - 1e-5f);
    float scale = atanhf(t) / (SQC * n);
    float ox = hv.x * scale, oy = hv.y * scale;
    *reinterpret_cast<float2*>(h_tan + base) = make_float2(ox, oy);
    f16x2 o16 = {(f16)ox, (f16)oy};
    *reinterpret_cast<f16x2*>(h_tan16 + base) = o16;
}

// ---------------------------------------------------------------------------
// CSR build (counting sort by dst), int atomics only
// ---------------------------------------------------------------------------
__global__ __launch_bounds__(256) void hist_kernel(const int* __restrict__ dst,
                                                   int* __restrict__ hist) {
    int t = blockIdx.y;
    int e = blockIdx.x * blockDim.x + threadIdx.x;
    if (e >= E_EDGES) return;
    atomicAdd(&hist[t * N_ENT + dst[(size_t)t * E_EDGES + e]], 1);
}

__global__ __launch_bounds__(1024) void scanA_kernel(const int* __restrict__ hist,
                                                     int* __restrict__ scanned,
                                                     int* __restrict__ partial) {
    __shared__ int s[1024];
    int t = blockIdx.y, blk = blockIdx.x, tid = threadIdx.x;
    int idx = blk * 1024 + tid;
    int v = (idx < N_ENT) ? hist[t * N_ENT + idx] : 0;
    s[tid] = v; __syncthreads();
    #pragma unroll
    for (int off = 1; off < 1024; off <<= 1) {
        int x = (tid >= off) ? s[tid - off] : 0;
        __syncthreads();
        s[tid] += x;
        __syncthreads();
    }
    scanned[t * NPAD + idx] = s[tid];
    if (tid == 1023) partial[t * 40 + blk] = s[1023];
}

__global__ __launch_bounds__(64) void scanB_kernel(int* __restrict__ partial) {
    int t = blockIdx.x, tid = threadIdx.x;
    int orig = (tid < 40) ? partial[t * 40 + tid] : 0;
    int v = orig;
    #pragma unroll
    for (int off = 1; off < 64; off <<= 1) {
        int x = __shfl_up(v, off, 64);
        if (tid >= off) v += x;
    }
    if (tid < 40) partial[t * 40 + tid] = v - orig;   // exclusive
}

__global__ __launch_bounds__(1024) void scanC_kernel(const int* __restrict__ hist,
                                                     const int* __restrict__ scanned,
                                                     const int* __restrict__ partial,
                                                     int* __restrict__ row_ptr,
                                                     int* __restrict__ cursor) {
    int t = blockIdx.y, blk = blockIdx.x, tid = threadIdx.x;
    int idx = blk * 1024 + tid;
    if (idx >= N_ENT) return;
    int incl = scanned[t * NPAD + idx] + partial[t * 40 + blk];
    row_ptr[t * (N_ENT + 1) + idx + 1] = incl;
    cursor[t * N_ENT + idx] = incl - hist[t * N_ENT + idx];
    if (idx == 0) row_ptr[t * (N_ENT + 1)] = 0;
}

// pack (src, rel) into one 32-bit word: src in [0,40000)<2^16, rel<480<2^9
__global__ __launch_bounds__(256) void scatter_kernel(const int* __restrict__ src,
                                                      const int* __restrict__ dst,
                                                      const int* __restrict__ rel,
                                                      int* __restrict__ cursor,
                                                      unsigned* __restrict__ sorted) {
    int t = blockIdx.y;
    int e = blockIdx.x * blockDim.x + threadIdx.x;
    if (e >= E_EDGES) return;
    size_t o = (size_t)t * E_EDGES + e;
    int d = dst[o];
    int pos = atomicAdd(&cursor[t * N_ENT + d], 1);
    sorted[(size_t)t * E_EDGES + pos] = (unsigned)src[o] | ((unsigned)rel[o] << 16);
}

// ---------------------------------------------------------------------------
// MFMA f16 GEMM: O{n,l,g}16 = A16 @ W{n,l,g}  (A staged in swizzled LDS)
// 256 thr = 4 waves, 64 rows/block. mfma(wf, af) -> lane holds 4 consecutive cols.
// ---------------------------------------------------------------------------
__global__ __launch_bounds__(256) void gemm3_kernel(
        const f16* __restrict__ A16, const f16* __restrict__ wpack,
        f16* __restrict__ On, f16* __restrict__ Ol, f16* __restrict__ Og) {
    __shared__ f16 a_s[64 * 128];        // 16 KB, XOR-swizzled (half-index ^ ((row&7)<<3))
    const int tid = threadIdx.x;
    const int rowBase = blockIdx.x * 64;

    // stage: thread t -> row r = t>>2, quarter q = t&3 (32 halves), 4x16B chunks
    {
        int r = tid >> 2, q = tid & 3;
        const float4* src = reinterpret_cast<const float4*>(A16 + (size_t)(rowBase + r) * D + q * 32);
        #pragma unroll
        for (int i = 0; i < 4; ++i) {
            int hoff = (q * 32 + i * 8) ^ ((r & 7) << 3);
            *reinterpret_cast<float4*>(&a_s[r * 128 + hoff]) = src[i];
        }
    }
    __syncthreads();

    const int wave = tid >> 6, lane = tid & 63;
    const int arow = wave * 16 + (lane & 15);

    f16x8 af[4];
    #pragma unroll
    for (int ks = 0; ks < 4; ++ks) {
        int hoff = (ks * 32 + (lane >> 4) * 8) ^ ((arow & 7) << 3);
        af[ks] = *reinterpret_cast<const f16x8*>(&a_s[arow * 128 + hoff]);
    }

    const int orow = rowBase + arow;
    const int colq = (lane >> 4) * 4;

    #pragma unroll
    for (int g = 0; g < 3; ++g) {
        f16* O = (g == 0) ? On : (g == 1) ? Ol : Og;
        #pragma unroll
        for (int nt = 0; nt < 8; ++nt) {
            f32x4 acc = {0.f, 0.f, 0.f, 0.f};
            #pragma unroll
            for (int ks = 0; ks < 4; ++ks) {
                const f16x8 wf = *reinterpret_cast<const f16x8*>(
                    wpack + ((((g * 8 + nt) * 4 + ks) * 64 + lane) << 3));
                acc = __builtin_amdgcn_mfma_f32_16x16x32_f16(wf, af[ks], acc, 0, 0, 0);
            }
            f16x4 o = {(f16)acc[0], (f16)acc[1], (f16)acc[2], (f16)acc[3]};
            *reinterpret_cast<f16x4*>(O + (size_t)orow * D + nt * 16 + colq) = o;
        }
    }
}

// ---------------------------------------------------------------------------
// Fused gather + update (state h_tan stays fp32; gather operands fp16)
// ---------------------------------------------------------------------------
__device__ __forceinline__ float wave_sum(float v) {
    #pragma unroll
    for (int off = 32; off >= 1; off >>= 1) v += __shfl_xor(v, off, 64);
    return v;
}

__global__ __launch_bounds__(256) void gather_update_kernel(
        float* __restrict__ h_tan, f16* __restrict__ h_tan16,
        const f16* __restrict__ hw_neigh, const f16* __restrict__ hw_loop,
        const f16* __restrict__ gate_pre, const f16* __restrict__ rel_w,
        const int* __restrict__ row_ptr, const unsigned* __restrict__ sorted,
        float* __restrict__ h_out, int write_h) {
    int wid  = (blockIdx.x * blockDim.x + threadIdx.x) >> 6;
    int lane = threadIdx.x & 63;
    if (wid >= N_ENT) return;
    int base = wid * D + lane * 2;
    int c2 = lane * 2;

    int beg = row_ptr[wid], end = row_ptr[wid + 1];
    float ax = 0.f, ay = 0.f;
    for (int e = beg; e < end; ++e) {
        unsigned v = sorted[e];                       // wave-broadcast
        int s = v & 0xFFFFu, r = v >> 16;
        f16x2 hv = *reinterpret_cast<const f16x2*>(hw_neigh + s * D + c2);
        f16x2 rv = *reinterpret_cast<const f16x2*>(rel_w    + r * D + c2);
        ax += (float)hv[0] + (float)rv[0];
        ay += (float)hv[1] + (float)rv[1];
    }
    float inv = 1.0f / fmaxf((float)(end - beg), 1.0f);

    f16x2  hl = *reinterpret_cast<const f16x2*>(hw_loop  + base);
    f16x2  gp = *reinterpret_cast<const f16x2*>(gate_pre + base);
    float2 ht = *reinterpret_cast<const float2*>(h_tan   + base);

    float ox = fmaf(ax, inv, (float)hl[0]);
    float oy = fmaf(ay, inv, (float)hl[1]);
    ox = (ox >= 0.f) ? ox : RRELU_SLOPE * ox;
    oy = (oy >= 0.f) ? oy : RRELU_SLOPE * oy;

    // expmap0(out_tan)
    float nu = fmaxf(sqrtf(wave_sum(ox * ox + oy * oy)), EPS_);
    float su = tanhf(SQC * nu) / (SQC * nu);
    float xx = ox * su, xy = oy * su;

    // logmap0(x)
    float nx = fmaxf(sqrtf(wave_sum(xx * xx + xy * xy)), EPS_);
    float tt = fminf(SQC * nx, 1.0f - 1e-5f);
    float sl = atanhf(tt) / (SQC * nx);
    float hnx = xx * sl, hny = xy * sl;

    // gate mix
    float gx = 1.0f / (1.0f + expf(-(float)gp[0]));
    float gy = 1.0f / (1.0f + expf(-(float)gp[1]));
    float mx = fmaf(gx, hnx - ht.x, ht.x);
    float my = fmaf(gy, hny - ht.y, ht.y);

    // h = expmap0(mixed)
    float nm = fmaxf(sqrtf(wave_sum(mx * mx + my * my)), EPS_);
    float sm = tanhf(SQC * nm) / (SQC * nm);
    float hx = mx * sm, hy = my * sm;

    if (write_h)
        *reinterpret_cast<float2*>(h_out + base) = make_float2(hx, hy);

    // h_tan(next) = logmap0(h) — exact reference chain, fp32 state
    float nh = fmaxf(sqrtf(wave_sum(hx * hx + hy * hy)), EPS_);
    float th = fminf(SQC * nh, 1.0f - 1e-5f);
    float slh = atanhf(th) / (SQC * nh);
    float ntx = hx * slh, nty = hy * slh;
    *reinterpret_cast<float2*>(h_tan + base) = make_float2(ntx, nty);
    f16x2 o16 = {(f16)ntx, (f16)nty};
    *reinterpret_cast<f16x2*>(h_tan16 + base) = o16;
}

// ---------------------------------------------------------------------------
extern "C" void kernel_launch(void* const* d_in, const int* in_sizes, int n_in,
                              void* d_out, int out_size, void* d_ws, size_t ws_size,
                              hipStream_t stream) {
    const int*   src  = (const int*)d_in[0];
    const int*   dst  = (const int*)d_in[1];
    const int*   rel  = (const int*)d_in[2];
    const float* dyn  = (const float*)d_in[3];
    const float* erel = (const float*)d_in[4];
    const float* wn   = (const float*)d_in[5];
    const float* wl   = (const float*)d_in[6];
    const float* wg   = (const float*)d_in[7];
    float* h = (float*)d_out;

    const size_t ND = (size_t)N_ENT * D;
    char* p = (char*)d_ws;
    float* h_tan    = (float*)p;            p += ND * 4;
    f16*   h_tan16  = (f16*)p;              p += ND * 2;
    f16*   hw_neigh = (f16*)p;              p += ND * 2;
    f16*   hw_loop  = (f16*)p;              p += ND * 2;
    f16*   gate_pre = (f16*)p;              p += ND * 2;
    f16*   rel_w16  = (f16*)p;              p += (size_t)N_REL2 * D * 2;
    f16*   wpack    = (f16*)p;              p += (size_t)3 * D * D * 2;
    unsigned* sorted= (unsigned*)p;         p += (size_t)T_STEPS * E_EDGES * 4;
    int*   hist     = (int*)p;              p += (size_t)T_STEPS * N_ENT * 4;
    int*   scanned  = (int*)p;              p += (size_t)T_STEPS * NPAD * 4;
    int*   partial  = (int*)p;              p += (size_t)T_STEPS * 64 * 4;
    int*   row_ptr  = (int*)p;              p += (size_t)T_STEPS * (N_ENT + 1) * 4;
    int*   cursor   = (int*)p;

    const int nodeBlocks = (N_ENT * 64 + 255) / 256;           // 10000
    const int edgeB      = (E_EDGES + 255) / 256;              // 782

    // CSR build (all 8 steps)
    hipMemsetAsync(hist, 0, (size_t)T_STEPS * N_ENT * sizeof(int), stream);
    hist_kernel<<<dim3(edgeB, T_STEPS), 256, 0, stream>>>(dst, hist);
    scanA_kernel<<<dim3(40, T_STEPS), 1024, 0, stream>>>(hist, scanned, partial);
    scanB_kernel<<<T_STEPS, 64, 0, stream>>>(partial);
    scanC_kernel<<<dim3(40, T_STEPS), 1024, 0, stream>>>(hist, scanned, partial, row_ptr, cursor);
    scatter_kernel<<<dim3(edgeB, T_STEPS), 256, 0, stream>>>(src, dst, rel, cursor, sorted);

    // loop-invariant precompute
    relw_kernel<<<N_REL2, D, 0, stream>>>(erel, wn, rel_w16);
    cvtw_kernel<<<192, 256, 0, stream>>>(wn, wl, wg, wpack);
    logmap_kernel<<<nodeBlocks, 256, 0, stream>>>(dyn, h_tan, h_tan16);

    for (int t = 0; t < T_STEPS; ++t) {
        gemm3_kernel<<<N_ENT / 64, 256, 0, stream>>>(
            h_tan16, wpack, hw_neigh, hw_loop, gate_pre);
        gather_update_kernel<<<nodeBlocks, 256, 0, stream>>>(
            h_tan, h_tan16, hw_neigh, hw_loop, gate_pre, rel_w16,
            row_ptr + t * (N_ENT + 1), sorted + (size_t)t * E_EDGES,
            h, (t == T_STEPS - 1) ? 1 : 0);
    }
}

// Round 5
// 807.584 us; speedup vs baseline: 4.7963x; 1.0307x over previous
//
#include <hip/hip_runtime.h>
#include <hip/hip_bf16.h>
#include <math.h>

#define N_ENT   40000
#define N_REL2  480
#define D       128
#define T_STEPS 8
#define E_EDGES 200000
#define SQC     0.1f                 // sqrt(C), C = 0.01
#define RRELU_SLOPE 0.22916666666666666f
#define EPS_    1e-6f
#define NPAD    40960                // 40 blocks x 1024 (scan padding)

typedef _Float16 f16;
typedef _Float16 f16x8 __attribute__((ext_vector_type(8)));
typedef _Float16 f16x4 __attribute__((ext_vector_type(4)));
typedef _Float16 f16x2 __attribute__((ext_vector_type(2)));
typedef float    f32x4 __attribute__((ext_vector_type(4)));

// ---------------------------------------------------------------------------
// rel_w16[r][c] = (f16) sum_k emb_rel[r][k] * w_neigh[k][c]
// ---------------------------------------------------------------------------
__global__ void relw_kernel(const float* __restrict__ emb_rel,
                            const float* __restrict__ w_neigh,
                            f16* __restrict__ rel_w16) {
    int row = blockIdx.x, col = threadIdx.x;
    float acc = 0.f;
    #pragma unroll 8
    for (int k = 0; k < D; ++k)
        acc = fmaf(emb_rel[row * D + k], w_neigh[k * D + col], acc);
    rel_w16[row * D + col] = (f16)acc;
}

// ---------------------------------------------------------------------------
// Wpack: fragment-layout fp16 pack of {wn,wl,wg}.
// pack[(((g*8+nt)*4+ks)*64 + lane)*8 + j] = Wg[ks*32+(lane>>4)*8+j][nt*16+(lane&15)]
// ---------------------------------------------------------------------------
__global__ __launch_bounds__(256) void cvtw_kernel(const float* __restrict__ wn,
                                                   const float* __restrict__ wl,
                                                   const float* __restrict__ wg,
                                                   f16* __restrict__ wpack) {
    int idx = blockIdx.x * blockDim.x + threadIdx.x;   // 0 .. 49151
    int j    = idx & 7;
    int lane = (idx >> 3) & 63;
    int ks   = (idx >> 9) & 3;
    int nt   = (idx >> 11) & 7;
    int g    = idx >> 14;
    const float* W = (g == 0) ? wn : (g == 1) ? wl : wg;
    int k = ks * 32 + (lane >> 4) * 8 + j;
    int n = nt * 16 + (lane & 15);
    wpack[idx] = (f16)W[k * D + n];
}

// ---------------------------------------------------------------------------
// logmap0 of initial h: h_tan (fp32) + h_tan16 (fp16)
// ---------------------------------------------------------------------------
__global__ __launch_bounds__(256) void logmap_kernel(const float* __restrict__ h,
                                                     float* __restrict__ h_tan,
                                                     f16* __restrict__ h_tan16) {
    int wid  = (blockIdx.x * blockDim.x + threadIdx.x) >> 6;
    int lane = threadIdx.x & 63;
    if (wid >= N_ENT) return;
    int base = wid * D + lane * 2;
    float2 hv = *reinterpret_cast<const float2*>(h + base);
    float ss = hv.x * hv.x + hv.y * hv.y;
    #pragma unroll
    for (int off = 32; off >= 1; off >>= 1) ss += __shfl_xor(ss, off, 64);
    float n = fmaxf(sqrtf(ss), EPS_);
    float t = fminf(SQC * n, 1.0f - 1e-5f);
    float scale = atanhf(t) / (SQC * n);
    float ox = hv.x * scale, oy = hv.y * scale;
    *reinterpret_cast<float2*>(h_tan + base) = make_float2(ox, oy);
    f16x2 o16 = {(f16)ox, (f16)oy};
    *reinterpret_cast<f16x2*>(h_tan16 + base) = o16;
}

// ---------------------------------------------------------------------------
// CSR build (counting sort by dst), int atomics only
// ---------------------------------------------------------------------------
__global__ __launch_bounds__(256) void hist_kernel(const int* __restrict__ dst,
                                                   int* __restrict__ hist) {
    int t = blockIdx.y;
    int e = blockIdx.x * blockDim.x + threadIdx.x;
    if (e >= E_EDGES) return;
    atomicAdd(&hist[t * N_ENT + dst[(size_t)t * E_EDGES + e]], 1);
}

__global__ __launch_bounds__(1024) void scanA_kernel(const int* __restrict__ hist,
                                                     int* __restrict__ scanned,
                                                     int* __restrict__ partial) {
    __shared__ int s[1024];
    int t = blockIdx.y, blk = blockIdx.x, tid = threadIdx.x;
    int idx = blk * 1024 + tid;
    int v = (idx < N_ENT) ? hist[t * N_ENT + idx] : 0;
    s[tid] = v; __syncthreads();
    #pragma unroll
    for (int off = 1; off < 1024; off <<= 1) {
        int x = (tid >= off) ? s[tid - off] : 0;
        __syncthreads();
        s[tid] += x;
        __syncthreads();
    }
    scanned[t * NPAD + idx] = s[tid];
    if (tid == 1023) partial[t * 40 + blk] = s[1023];
}

__global__ __launch_bounds__(64) void scanB_kernel(int* __restrict__ partial) {
    int t = blockIdx.x, tid = threadIdx.x;
    int orig = (tid < 40) ? partial[t * 40 + tid] : 0;
    int v = orig;
    #pragma unroll
    for (int off = 1; off < 64; off <<= 1) {
        int x = __shfl_up(v, off, 64);
        if (tid >= off) v += x;
    }
    if (tid < 40) partial[t * 40 + tid] = v - orig;   // exclusive
}

__global__ __launch_bounds__(1024) void scanC_kernel(const int* __restrict__ hist,
                                                     const int* __restrict__ scanned,
                                                     const int* __restrict__ partial,
                                                     int* __restrict__ row_ptr,
                                                     int* __restrict__ cursor) {
    int t = blockIdx.y, blk = blockIdx.x, tid = threadIdx.x;
    int idx = blk * 1024 + tid;
    if (idx >= N_ENT) return;
    int incl = scanned[t * NPAD + idx] + partial[t * 40 + blk];
    row_ptr[t * (N_ENT + 1) + idx + 1] = incl;
    cursor[t * N_ENT + idx] = incl - hist[t * N_ENT + idx];
    if (idx == 0) row_ptr[t * (N_ENT + 1)] = 0;
}

// pack (src, rel) into one 32-bit word: src < 2^16, rel < 2^9
__global__ __launch_bounds__(256) void scatter_kernel(const int* __restrict__ src,
                                                      const int* __restrict__ dst,
                                                      const int* __restrict__ rel,
                                                      int* __restrict__ cursor,
                                                      unsigned* __restrict__ sorted) {
    int t = blockIdx.y;
    int e = blockIdx.x * blockDim.x + threadIdx.x;
    if (e >= E_EDGES) return;
    size_t o = (size_t)t * E_EDGES + e;
    int d = dst[o];
    int pos = atomicAdd(&cursor[t * N_ENT + d], 1);
    unsigned payload = (unsigned)src[o] | ((unsigned)rel[o] << 16);
    __builtin_nontemporal_store(payload, &sorted[(size_t)t * E_EDGES + pos]);
}

// ---------------------------------------------------------------------------
// MFMA f16 GEMM: O{n,l,g}16 = A16 @ W{n,l,g}  (A staged in swizzled LDS)
// ---------------------------------------------------------------------------
__global__ __launch_bounds__(256) void gemm3_kernel(
        const f16* __restrict__ A16, const f16* __restrict__ wpack,
        f16* __restrict__ On, f16* __restrict__ Ol, f16* __restrict__ Og) {
    __shared__ f16 a_s[64 * 128];        // 16 KB, XOR-swizzled (half-index ^ ((row&7)<<3))
    const int tid = threadIdx.x;
    const int rowBase = blockIdx.x * 64;

    {
        int r = tid >> 2, q = tid & 3;
        const float4* src = reinterpret_cast<const float4*>(A16 + (size_t)(rowBase + r) * D + q * 32);
        #pragma unroll
        for (int i = 0; i < 4; ++i) {
            int hoff = (q * 32 + i * 8) ^ ((r & 7) << 3);
            *reinterpret_cast<float4*>(&a_s[r * 128 + hoff]) = src[i];
        }
    }
    __syncthreads();

    const int wave = tid >> 6, lane = tid & 63;
    const int arow = wave * 16 + (lane & 15);

    f16x8 af[4];
    #pragma unroll
    for (int ks = 0; ks < 4; ++ks) {
        int hoff = (ks * 32 + (lane >> 4) * 8) ^ ((arow & 7) << 3);
        af[ks] = *reinterpret_cast<const f16x8*>(&a_s[arow * 128 + hoff]);
    }

    const int orow = rowBase + arow;
    const int colq = (lane >> 4) * 4;

    #pragma unroll
    for (int g = 0; g < 3; ++g) {
        f16* O = (g == 0) ? On : (g == 1) ? Ol : Og;
        #pragma unroll
        for (int nt = 0; nt < 8; ++nt) {
            f32x4 acc = {0.f, 0.f, 0.f, 0.f};
            #pragma unroll
            for (int ks = 0; ks < 4; ++ks) {
                const f16x8 wf = *reinterpret_cast<const f16x8*>(
                    wpack + ((((g * 8 + nt) * 4 + ks) * 64 + lane) << 3));
                acc = __builtin_amdgcn_mfma_f32_16x16x32_f16(wf, af[ks], acc, 0, 0, 0);
            }
            f16x4 o = {(f16)acc[0], (f16)acc[1], (f16)acc[2], (f16)acc[3]};
            *reinterpret_cast<f16x4*>(O + (size_t)orow * D + nt * 16 + colq) = o;
        }
    }
}

// ---------------------------------------------------------------------------
// Fused gather + update. Gather: 4 edges/iter, 16 lanes/edge, f16x8 loads,
// fp32 accum; shfl-tree reduce + per-wave LDS redistribution to 2-col/lane.
// ---------------------------------------------------------------------------
__device__ __forceinline__ float wave_sum(float v) {
    #pragma unroll
    for (int off = 32; off >= 1; off >>= 1) v += __shfl_xor(v, off, 64);
    return v;
}

__global__ __launch_bounds__(256) void gather_update_kernel(
        float* __restrict__ h_tan, f16* __restrict__ h_tan16,
        const f16* __restrict__ hw_neigh, const f16* __restrict__ hw_loop,
        const f16* __restrict__ gate_pre, const f16* __restrict__ rel_w,
        const int* __restrict__ row_ptr, const unsigned* __restrict__ sorted,
        float* __restrict__ h_out, int write_h) {
    __shared__ float agg_s[4][128];      // per-wave redistribution buffer
    int wid  = (blockIdx.x * blockDim.x + threadIdx.x) >> 6;
    int lane = threadIdx.x & 63;
    int wv   = (threadIdx.x >> 6) & 3;
    if (wid >= N_ENT) return;
    int base = wid * D + lane * 2;

    int beg = row_ptr[wid], end = row_ptr[wid + 1];

    // --- gather: edge slot g = lane>>4 (4 edges/iter), col block cb = lane&15
    const int cb8 = (lane & 15) * 8;     // 8 halves per lane
    float acc[8];
    #pragma unroll
    for (int j = 0; j < 8; ++j) acc[j] = 0.f;

    for (int e = beg; e < end; e += 4) {
        int idx = e + (lane >> 4);
        bool valid = idx < end;
        unsigned v = sorted[valid ? idx : beg];
        int s = v & 0xFFFFu, r = v >> 16;
        const f16x8 hv = *reinterpret_cast<const f16x8*>(hw_neigh + s * D + cb8);
        const f16x8 rv = *reinterpret_cast<const f16x8*>(rel_w    + r * D + cb8);
        float m = valid ? 1.f : 0.f;
        #pragma unroll
        for (int j = 0; j < 8; ++j)
            acc[j] = fmaf(m, (float)hv[j] + (float)rv[j], acc[j]);
    }
    // reduce across the 4 edge-slot groups (lanes differing in bits 4,5)
    #pragma unroll
    for (int j = 0; j < 8; ++j) {
        acc[j] += __shfl_xor(acc[j], 16, 64);
        acc[j] += __shfl_xor(acc[j], 32, 64);
    }
    // redistribute: lanes 0..15 hold col blocks 0..15 -> LDS -> 2 cols/lane
    if (lane < 16) {
        f32x4 lo = {acc[0], acc[1], acc[2], acc[3]};
        f32x4 hi = {acc[4], acc[5], acc[6], acc[7]};
        *reinterpret_cast<f32x4*>(&agg_s[wv][cb8])     = lo;
        *reinterpret_cast<f32x4*>(&agg_s[wv][cb8 + 4]) = hi;
    }
    float2 ag = *reinterpret_cast<const float2*>(&agg_s[wv][lane * 2]);

    float inv = 1.0f / fmaxf((float)(end - beg), 1.0f);

    f16x2  hl = *reinterpret_cast<const f16x2*>(hw_loop  + base);
    f16x2  gp = *reinterpret_cast<const f16x2*>(gate_pre + base);
    float2 ht = *reinterpret_cast<const float2*>(h_tan   + base);

    float ox = fmaf(ag.x, inv, (float)hl[0]);
    float oy = fmaf(ag.y, inv, (float)hl[1]);
    ox = (ox >= 0.f) ? ox : RRELU_SLOPE * ox;
    oy = (oy >= 0.f) ? oy : RRELU_SLOPE * oy;

    // expmap0(out_tan)
    float nu = fmaxf(sqrtf(wave_sum(ox * ox + oy * oy)), EPS_);
    float su = tanhf(SQC * nu) / (SQC * nu);
    float xx = ox * su, xy = oy * su;

    // logmap0(x)
    float nx = fmaxf(sqrtf(wave_sum(xx * xx + xy * xy)), EPS_);
    float tt = fminf(SQC * nx, 1.0f - 1e-5f);
    float sl = atanhf(tt) / (SQC * nx);
    float hnx = xx * sl, hny = xy * sl;

    // gate mix
    float gx = 1.0f / (1.0f + expf(-(float)gp[0]));
    float gy = 1.0f / (1.0f + expf(-(float)gp[1]));
    float mx = fmaf(gx, hnx - ht.x, ht.x);
    float my = fmaf(gy, hny - ht.y, ht.y);

    // h = expmap0(mixed)
    float nm = fmaxf(sqrtf(wave_sum(mx * mx + my * my)), EPS_);
    float sm = tanhf(SQC * nm) / (SQC * nm);
    float hx = mx * sm, hy = my * sm;

    if (write_h)
        *reinterpret_cast<float2*>(h_out + base) = make_float2(hx, hy);

    // h_tan(next) = logmap0(h) — exact reference chain, fp32 state
    float nh = fmaxf(sqrtf(wave_sum(hx * hx + hy * hy)), EPS_);
    float th = fminf(SQC * nh, 1.0f - 1e-5f);
    float slh = atanhf(th) / (SQC * nh);
    float ntx = hx * slh, nty = hy * slh;
    *reinterpret_cast<float2*>(h_tan + base) = make_float2(ntx, nty);
    f16x2 o16 = {(f16)ntx, (f16)nty};
    *reinterpret_cast<f16x2*>(h_tan16 + base) = o16;
}

// ---------------------------------------------------------------------------
extern "C" void kernel_launch(void* const* d_in, const int* in_sizes, int n_in,
                              void* d_out, int out_size, void* d_ws, size_t ws_size,
                              hipStream_t stream) {
    const int*   src  = (const int*)d_in[0];
    const int*   dst  = (const int*)d_in[1];
    const int*   rel  = (const int*)d_in[2];
    const float* dyn  = (const float*)d_in[3];
    const float* erel = (const float*)d_in[4];
    const float* wn   = (const float*)d_in[5];
    const float* wl   = (const float*)d_in[6];
    const float* wg   = (const float*)d_in[7];
    float* h = (float*)d_out;

    const size_t ND = (size_t)N_ENT * D;
    char* p = (char*)d_ws;
    float* h_tan    = (float*)p;            p += ND * 4;
    f16*   h_tan16  = (f16*)p;              p += ND * 2;
    f16*   hw_neigh = (f16*)p;              p += ND * 2;
    f16*   hw_loop  = (f16*)p;              p += ND * 2;
    f16*   gate_pre = (f16*)p;              p += ND * 2;
    f16*   rel_w16  = (f16*)p;              p += (size_t)N_REL2 * D * 2;
    f16*   wpack    = (f16*)p;              p += (size_t)3 * D * D * 2;
    unsigned* sorted= (unsigned*)p;         p += (size_t)T_STEPS * E_EDGES * 4;
    int*   hist     = (int*)p;              p += (size_t)T_STEPS * N_ENT * 4;
    int*   scanned  = (int*)p;              p += (size_t)T_STEPS * NPAD * 4;
    int*   partial  = (int*)p;              p += (size_t)T_STEPS * 64 * 4;
    int*   row_ptr  = (int*)p;              p += (size_t)T_STEPS * (N_ENT + 1) * 4;
    int*   cursor   = (int*)p;

    const int nodeBlocks = (N_ENT * 64 + 255) / 256;           // 10000
    const int edgeB      = (E_EDGES + 255) / 256;              // 782

    // CSR build (all 8 steps)
    hipMemsetAsync(hist, 0, (size_t)T_STEPS * N_ENT * sizeof(int), stream);
    hist_kernel<<<dim3(edgeB, T_STEPS), 256, 0, stream>>>(dst, hist);
    scanA_kernel<<<dim3(40, T_STEPS), 1024, 0, stream>>>(hist, scanned, partial);
    scanB_kernel<<<T_STEPS, 64, 0, stream>>>(partial);
    scanC_kernel<<<dim3(40, T_STEPS), 1024, 0, stream>>>(hist, scanned, partial, row_ptr, cursor);
    scatter_kernel<<<dim3(edgeB, T_STEPS), 256, 0, stream>>>(src, dst, rel, cursor, sorted);

    // loop-invariant precompute
    relw_kernel<<<N_REL2, D, 0, stream>>>(erel, wn, rel_w16);
    cvtw_kernel<<<192, 256, 0, stream>>>(wn, wl, wg, wpack);
    logmap_kernel<<<nodeBlocks, 256, 0, stream>>>(dyn, h_tan, h_tan16);

    for (int t = 0; t < T_STEPS; ++t) {
        gemm3_kernel<<<N_ENT / 64, 256, 0, stream>>>(
            h_tan16, wpack, hw_neigh, hw_loop, gate_pre);
        gather_update_kernel<<<nodeBlocks, 256, 0, stream>>>(
            h_tan, h_tan16, hw_neigh, hw_loop, gate_pre, rel_w16,
            row_ptr + t * (N_ENT + 1), sorted + (size_t)t * E_EDGES,
            h, (t == T_STEPS - 1) ? 1 : 0);
    }
}

// Round 8
// 688.880 us; speedup vs baseline: 5.6228x; 1.1723x over previous
//
#include <hip/hip_runtime.h>
#include <hip/hip_bf16.h>
#include <math.h>

#define N_ENT   40000
#define N_REL2  480
#define D       128
#define T_STEPS 8
#define E_EDGES 200000
#define SQC     0.1f                 // sqrt(C), C = 0.01
#define RRELU_SLOPE 0.22916666666666666f
#define EPS_    1e-6f
#define NPAD    40960                // 40 blocks x 1024 (scan padding)

typedef _Float16 f16;
typedef _Float16 f16x8 __attribute__((ext_vector_type(8)));
typedef _Float16 f16x4 __attribute__((ext_vector_type(4)));
typedef _Float16 f16x2 __attribute__((ext_vector_type(2)));
typedef float    f32x4 __attribute__((ext_vector_type(4)));

// ---------------------------------------------------------------------------
// rel_w16[r][c] = (f16) sum_k emb_rel[r][k] * w_neigh[k][c]
// ---------------------------------------------------------------------------
__global__ void relw_kernel(const float* __restrict__ emb_rel,
                            const float* __restrict__ w_neigh,
                            f16* __restrict__ rel_w16) {
    int row = blockIdx.x, col = threadIdx.x;
    float acc = 0.f;
    #pragma unroll 8
    for (int k = 0; k < D; ++k)
        acc = fmaf(emb_rel[row * D + k], w_neigh[k * D + col], acc);
    rel_w16[row * D + col] = (f16)acc;
}

// ---------------------------------------------------------------------------
// Wpack: fragment-layout fp16 pack of {wn,wl,wg}.
// ---------------------------------------------------------------------------
__global__ __launch_bounds__(256) void cvtw_kernel(const float* __restrict__ wn,
                                                   const float* __restrict__ wl,
                                                   const float* __restrict__ wg,
                                                   f16* __restrict__ wpack) {
    int idx = blockIdx.x * blockDim.x + threadIdx.x;   // 0 .. 49151
    int j    = idx & 7;
    int lane = (idx >> 3) & 63;
    int ks   = (idx >> 9) & 3;
    int nt   = (idx >> 11) & 7;
    int g    = idx >> 14;
    const float* W = (g == 0) ? wn : (g == 1) ? wl : wg;
    int k = ks * 32 + (lane >> 4) * 8 + j;
    int n = nt * 16 + (lane & 15);
    wpack[idx] = (f16)W[k * D + n];
}

// ---------------------------------------------------------------------------
// logmap0 of initial h: h_tan (fp32) + h_tan16 (fp16)
// ---------------------------------------------------------------------------
__global__ __launch_bounds__(256) void logmap_kernel(const float* __restrict__ h,
                                                     float* __restrict__ h_tan,
                                                     f16* __restrict__ h_tan16) {
    int wid  = (blockIdx.x * blockDim.x + threadIdx.x) >> 6;
    int lane = threadIdx.x & 63;
    if (wid >= N_ENT) return;
    int base = wid * D + lane * 2;
    float2 hv = *reinterpret_cast<const float2*>(h + base);
    float ss = hv.x * hv.x + hv.y * hv.y;
    #pragma unroll
    for (int off = 32; off >= 1; off >>= 1) ss += __shfl_xor(ss, off, 64);
    float n = fmaxf(sqrtf(ss), EPS_);
    float t = fminf(SQC * n, 1.0f - 1e-5f);
    float scale = atanhf(t) / (SQC * n);
    float ox = hv.x * scale, oy = hv.y * scale;
    *reinterpret_cast<float2*>(h_tan + base) = make_float2(ox, oy);
    f16x2 o16 = {(f16)ox, (f16)oy};
    *reinterpret_cast<f16x2*>(h_tan16 + base) = o16;
}

// ---------------------------------------------------------------------------
// CSR build (counting sort by dst), int atomics only
// ---------------------------------------------------------------------------
__global__ __launch_bounds__(256) void hist_kernel(const int* __restrict__ dst,
                                                   int* __restrict__ hist) {
    int t = blockIdx.y;
    int e = blockIdx.x * blockDim.x + threadIdx.x;
    if (e >= E_EDGES) return;
    atomicAdd(&hist[t * N_ENT + dst[(size_t)t * E_EDGES + e]], 1);
}

__global__ __launch_bounds__(1024) void scanA_kernel(const int* __restrict__ hist,
                                                     int* __restrict__ scanned,
                                                     int* __restrict__ partial) {
    __shared__ int s[1024];
    int t = blockIdx.y, blk = blockIdx.x, tid = threadIdx.x;
    int idx = blk * 1024 + tid;
    int v = (idx < N_ENT) ? hist[t * N_ENT + idx] : 0;
    s[tid] = v; __syncthreads();
    #pragma unroll
    for (int off = 1; off < 1024; off <<= 1) {
        int x = (tid >= off) ? s[tid - off] : 0;
        __syncthreads();
        s[tid] += x;
        __syncthreads();
    }
    scanned[t * NPAD + idx] = s[tid];
    if (tid == 1023) partial[t * 40 + blk] = s[1023];
}

__global__ __launch_bounds__(64) void scanB_kernel(int* __restrict__ partial) {
    int t = blockIdx.x, tid = threadIdx.x;
    int orig = (tid < 40) ? partial[t * 40 + tid] : 0;
    int v = orig;
    #pragma unroll
    for (int off = 1; off < 64; off <<= 1) {
        int x = __shfl_up(v, off, 64);
        if (tid >= off) v += x;
    }
    if (tid < 40) partial[t * 40 + tid] = v - orig;   // exclusive
}

__global__ __launch_bounds__(1024) void scanC_kernel(const int* __restrict__ hist,
                                                     const int* __restrict__ scanned,
                                                     const int* __restrict__ partial,
                                                     int* __restrict__ row_ptr,
                                                     int* __restrict__ cursor) {
    int t = blockIdx.y, blk = blockIdx.x, tid = threadIdx.x;
    int idx = blk * 1024 + tid;
    if (idx >= N_ENT) return;
    int incl = scanned[t * NPAD + idx] + partial[t * 40 + blk];
    row_ptr[t * (N_ENT + 1) + idx + 1] = incl;
    cursor[t * N_ENT + idx] = incl - hist[t * N_ENT + idx];
    if (idx == 0) row_ptr[t * (N_ENT + 1)] = 0;
}

// pack (src, rel) into one 32-bit word: src < 2^16, rel < 2^9
__global__ __launch_bounds__(256) void scatter_kernel(const int* __restrict__ src,
                                                      const int* __restrict__ dst,
                                                      const int* __restrict__ rel,
                                                      int* __restrict__ cursor,
                                                      unsigned* __restrict__ sorted) {
    int t = blockIdx.y;
    int e = blockIdx.x * blockDim.x + threadIdx.x;
    if (e >= E_EDGES) return;
    size_t o = (size_t)t * E_EDGES + e;
    int d = dst[o];
    int pos = atomicAdd(&cursor[t * N_ENT + d], 1);
    sorted[(size_t)t * E_EDGES + pos] = (unsigned)src[o] | ((unsigned)rel[o] << 16);
}

// ---------------------------------------------------------------------------
// MFMA f16 GEMM: O{n,l,g}16 = A16 @ W{n,l,g}  (A staged in swizzled LDS)
// ---------------------------------------------------------------------------
__global__ __launch_bounds__(256) void gemm3_kernel(
        const f16* __restrict__ A16, const f16* __restrict__ wpack,
        f16* __restrict__ On, f16* __restrict__ Ol, f16* __restrict__ Og) {
    __shared__ f16 a_s[64 * 128];        // 16 KB, XOR-swizzled (half-index ^ ((row&7)<<3))
    const int tid = threadIdx.x;
    const int rowBase = blockIdx.x * 64;

    {
        int r = tid >> 2, q = tid & 3;
        const float4* src = reinterpret_cast<const float4*>(A16 + (size_t)(rowBase + r) * D + q * 32);
        #pragma unroll
        for (int i = 0; i < 4; ++i) {
            int hoff = (q * 32 + i * 8) ^ ((r & 7) << 3);
            *reinterpret_cast<float4*>(&a_s[r * 128 + hoff]) = src[i];
        }
    }
    __syncthreads();

    const int wave = tid >> 6, lane = tid & 63;
    const int arow = wave * 16 + (lane & 15);

    f16x8 af[4];
    #pragma unroll
    for (int ks = 0; ks < 4; ++ks) {
        int hoff = (ks * 32 + (lane >> 4) * 8) ^ ((arow & 7) << 3);
        af[ks] = *reinterpret_cast<const f16x8*>(&a_s[arow * 128 + hoff]);
    }

    const int orow = rowBase + arow;
    const int colq = (lane >> 4) * 4;

    #pragma unroll
    for (int g = 0; g < 3; ++g) {
        f16* O = (g == 0) ? On : (g == 1) ? Ol : Og;
        #pragma unroll
        for (int nt = 0; nt < 8; ++nt) {
            f32x4 acc = {0.f, 0.f, 0.f, 0.f};
            #pragma unroll
            for (int ks = 0; ks < 4; ++ks) {
                const f16x8 wf = *reinterpret_cast<const f16x8*>(
                    wpack + ((((g * 8 + nt) * 4 + ks) * 64 + lane) << 3));
                acc = __builtin_amdgcn_mfma_f32_16x16x32_f16(wf, af[ks], acc, 0, 0, 0);
            }
            f16x4 o = {(f16)acc[0], (f16)acc[1], (f16)acc[2], (f16)acc[3]};
            *reinterpret_cast<f16x4*>(O + (size_t)orow * D + nt * 16 + colq) = o;
        }
    }
}

// ---------------------------------------------------------------------------
// Fused gather + tangent-space mix (roundtrip logmap0∘expmap0 == identity):
//   out  = rrelu(agg/cnt + h_tan@w_loop)
//   h_tan' = sigmoid(gate_pre)*out + (1-sigmoid)*h_tan
// Final step only: h_out = expmap0(h_tan')
// Wave per node; lane = (slot = lane>>4, colblock cb8 = (lane&15)*8).
// ---------------------------------------------------------------------------
__global__ __launch_bounds__(256) void gather_mix_kernel(
        float* __restrict__ h_tan, f16* __restrict__ h_tan16,
        const f16* __restrict__ hw_neigh, const f16* __restrict__ hw_loop,
        const f16* __restrict__ gate_pre, const f16* __restrict__ rel_w,
        const int* __restrict__ row_ptr, const unsigned* __restrict__ sorted,
        float* __restrict__ h_out, int last) {
    int wid  = (blockIdx.x * blockDim.x + threadIdx.x) >> 6;
    int lane = threadIdx.x & 63;
    if (wid >= N_ENT) return;

    const int cb8 = (lane & 15) * 8;
    int beg = row_ptr[wid], end = row_ptr[wid + 1];

    float acc[8];
    #pragma unroll
    for (int j = 0; j < 8; ++j) acc[j] = 0.f;

    for (int e = beg; e < end; e += 4) {
        int idx = e + (lane >> 4);
        bool valid = idx < end;
        unsigned v = sorted[valid ? idx : beg];
        int s = v & 0xFFFFu, r = v >> 16;
        const f16x8 hv = *reinterpret_cast<const f16x8*>(hw_neigh + s * D + cb8);
        const f16x8 rv = *reinterpret_cast<const f16x8*>(rel_w    + r * D + cb8);
        float m = valid ? 1.f : 0.f;
        #pragma unroll
        for (int j = 0; j < 8; ++j)
            acc[j] = fmaf(m, (float)hv[j] + (float)rv[j], acc[j]);
    }
    // reduce the 4 edge-slot groups (lanes differing in bits 4,5)
    #pragma unroll
    for (int j = 0; j < 8; ++j) {
        acc[j] += __shfl_xor(acc[j], 16, 64);
        acc[j] += __shfl_xor(acc[j], 32, 64);
    }

    if (lane < 16) {                     // epilogue: 16 lanes x 8 cols
        const size_t b = (size_t)wid * D + cb8;
        float inv = 1.0f / fmaxf((float)(end - beg), 1.0f);
        f16x8 hl = *reinterpret_cast<const f16x8*>(hw_loop  + b);
        f16x8 gp = *reinterpret_cast<const f16x8*>(gate_pre + b);
        f32x4 ht0 = *reinterpret_cast<const f32x4*>(h_tan + b);
        f32x4 ht1 = *reinterpret_cast<const f32x4*>(h_tan + b + 4);

        float mixed[8];
        #pragma unroll
        for (int j = 0; j < 8; ++j) {
            float o = fmaf(acc[j], inv, (float)hl[j]);
            o = (o >= 0.f) ? o : RRELU_SLOPE * o;
            float g = 1.0f / (1.0f + expf(-(float)gp[j]));
            float htj = (j < 4) ? ht0[j] : ht1[j - 4];
            mixed[j] = fmaf(g, o - htj, htj);
        }

        if (!last) {
            f32x4 m0 = {mixed[0], mixed[1], mixed[2], mixed[3]};
            f32x4 m1 = {mixed[4], mixed[5], mixed[6], mixed[7]};
            *reinterpret_cast<f32x4*>(h_tan + b)     = m0;
            *reinterpret_cast<f32x4*>(h_tan + b + 4) = m1;
            f16x8 m16 = {(f16)mixed[0], (f16)mixed[1], (f16)mixed[2], (f16)mixed[3],
                         (f16)mixed[4], (f16)mixed[5], (f16)mixed[6], (f16)mixed[7]};
            *reinterpret_cast<f16x8*>(h_tan16 + b) = m16;
        } else {
            // h_out = expmap0(mixed)
            float ss = 0.f;
            #pragma unroll
            for (int j = 0; j < 8; ++j) ss = fmaf(mixed[j], mixed[j], ss);
            ss += __shfl_xor(ss, 1, 64);
            ss += __shfl_xor(ss, 2, 64);
            ss += __shfl_xor(ss, 4, 64);
            ss += __shfl_xor(ss, 8, 64);
            float n = fmaxf(sqrtf(ss), EPS_);
            float s = tanhf(SQC * n) / (SQC * n);
            f32x4 o0 = {mixed[0] * s, mixed[1] * s, mixed[2] * s, mixed[3] * s};
            f32x4 o1 = {mixed[4] * s, mixed[5] * s, mixed[6] * s, mixed[7] * s};
            *reinterpret_cast<f32x4*>(h_out + b)     = o0;
            *reinterpret_cast<f32x4*>(h_out + b + 4) = o1;
        }
    }
}

// ---------------------------------------------------------------------------
extern "C" void kernel_launch(void* const* d_in, const int* in_sizes, int n_in,
                              void* d_out, int out_size, void* d_ws, size_t ws_size,
                              hipStream_t stream) {
    const int*   src  = (const int*)d_in[0];
    const int*   dst  = (const int*)d_in[1];
    const int*   rel  = (const int*)d_in[2];
    const float* dyn  = (const float*)d_in[3];
    const float* erel = (const float*)d_in[4];
    const float* wn   = (const float*)d_in[5];
    const float* wl   = (const float*)d_in[6];
    const float* wg   = (const float*)d_in[7];
    float* h = (float*)d_out;

    const size_t ND = (size_t)N_ENT * D;
    char* p = (char*)d_ws;
    float* h_tan    = (float*)p;            p += ND * 4;
    f16*   h_tan16  = (f16*)p;              p += ND * 2;
    f16*   hw_neigh = (f16*)p;              p += ND * 2;
    f16*   hw_loop  = (f16*)p;              p += ND * 2;
    f16*   gate_pre = (f16*)p;              p += ND * 2;
    f16*   rel_w16  = (f16*)p;              p += (size_t)N_REL2 * D * 2;
    f16*   wpack    = (f16*)p;              p += (size_t)3 * D * D * 2;
    unsigned* sorted= (unsigned*)p;         p += (size_t)T_STEPS * E_EDGES * 4;
    int*   hist     = (int*)p;              p += (size_t)T_STEPS * N_ENT * 4;
    int*   scanned  = (int*)p;              p += (size_t)T_STEPS * NPAD * 4;
    int*   partial  = (int*)p;              p += (size_t)T_STEPS * 64 * 4;
    int*   row_ptr  = (int*)p;              p += (size_t)T_STEPS * (N_ENT + 1) * 4;
    int*   cursor   = (int*)p;

    const int nodeBlocks = (N_ENT * 64 + 255) / 256;           // 10000
    const int edgeB      = (E_EDGES + 255) / 256;              // 782

    // CSR build (all 8 steps)
    hipMemsetAsync(hist, 0, (size_t)T_STEPS * N_ENT * sizeof(int), stream);
    hist_kernel<<<dim3(edgeB, T_STEPS), 256, 0, stream>>>(dst, hist);
    scanA_kernel<<<dim3(40, T_STEPS), 1024, 0, stream>>>(hist, scanned, partial);
    scanB_kernel<<<T_STEPS, 64, 0, stream>>>(partial);
    scanC_kernel<<<dim3(40, T_STEPS), 1024, 0, stream>>>(hist, scanned, partial, row_ptr, cursor);
    scatter_kernel<<<dim3(edgeB, T_STEPS), 256, 0, stream>>>(src, dst, rel, cursor, sorted);

    // loop-invariant precompute
    relw_kernel<<<N_REL2, D, 0, stream>>>(erel, wn, rel_w16);
    cvtw_kernel<<<192, 256, 0, stream>>>(wn, wl, wg, wpack);
    logmap_kernel<<<nodeBlocks, 256, 0, stream>>>(dyn, h_tan, h_tan16);

    for (int t = 0; t < T_STEPS; ++t) {
        gemm3_kernel<<<N_ENT / 64, 256, 0, stream>>>(
            h_tan16, wpack, hw_neigh, hw_loop, gate_pre);
        gather_mix_kernel<<<nodeBlocks, 256, 0, stream>>>(
            h_tan, h_tan16, hw_neigh, hw_loop, gate_pre, rel_w16,
            row_ptr + t * (N_ENT + 1), sorted + (size_t)t * E_EDGES,
            h, (t == T_STEPS - 1) ? 1 : 0);
    }
}

// Round 9
// 571.632 us; speedup vs baseline: 6.7761x; 1.2051x over previous
//
#include <hip/hip_runtime.h>
#include <hip/hip_bf16.h>
#include <math.h>

#define N_ENT   40000
#define N_REL2  480
#define D       128
#define T_STEPS 8
#define E_EDGES 200000
#define SQC     0.1f                 // sqrt(C), C = 0.01
#define RRELU_SLOPE 0.22916666666666666f
#define EPS_    1e-6f
#define NPAD    40960                // 40 blocks x 1024 (scan padding)

typedef _Float16 f16;
typedef _Float16 f16x8 __attribute__((ext_vector_type(8)));
typedef _Float16 f16x4 __attribute__((ext_vector_type(4)));
typedef _Float16 f16x2 __attribute__((ext_vector_type(2)));
typedef float    f32x4 __attribute__((ext_vector_type(4)));

// ---------------------------------------------------------------------------
// emb_rel16 = (f16) emb_rel
// ---------------------------------------------------------------------------
__global__ __launch_bounds__(256) void cvt_rel_kernel(const float* __restrict__ emb_rel,
                                                      f16* __restrict__ emb_rel16) {
    int i = blockIdx.x * blockDim.x + threadIdx.x;
    if (i < N_REL2 * D) emb_rel16[i] = (f16)emb_rel[i];
}

// ---------------------------------------------------------------------------
// Wpack: fragment-layout fp16 pack of {wn,wl,wg}.
// pack[(((g*8+nt)*4+ks)*64 + lane)*8 + j] = Wg[ks*32+(lane>>4)*8+j][nt*16+(lane&15)]
// ---------------------------------------------------------------------------
__global__ __launch_bounds__(256) void cvtw_kernel(const float* __restrict__ wn,
                                                   const float* __restrict__ wl,
                                                   const float* __restrict__ wg,
                                                   f16* __restrict__ wpack) {
    int idx = blockIdx.x * blockDim.x + threadIdx.x;   // 0 .. 49151
    int j    = idx & 7;
    int lane = (idx >> 3) & 63;
    int ks   = (idx >> 9) & 3;
    int nt   = (idx >> 11) & 7;
    int g    = idx >> 14;
    const float* W = (g == 0) ? wn : (g == 1) ? wl : wg;
    int k = ks * 32 + (lane >> 4) * 8 + j;
    int n = nt * 16 + (lane & 15);
    wpack[idx] = (f16)W[k * D + n];
}

// ---------------------------------------------------------------------------
// logmap0 of initial h: h_tan (fp32) + h_tan16 (fp16)
// ---------------------------------------------------------------------------
__global__ __launch_bounds__(256) void logmap_kernel(const float* __restrict__ h,
                                                     float* __restrict__ h_tan,
                                                     f16* __restrict__ h_tan16) {
    int wid  = (blockIdx.x * blockDim.x + threadIdx.x) >> 6;
    int lane = threadIdx.x & 63;
    if (wid >= N_ENT) return;
    int base = wid * D + lane * 2;
    float2 hv = *reinterpret_cast<const float2*>(h + base);
    float ss = hv.x * hv.x + hv.y * hv.y;
    #pragma unroll
    for (int off = 32; off >= 1; off >>= 1) ss += __shfl_xor(ss, off, 64);
    float n = fmaxf(sqrtf(ss), EPS_);
    float t = fminf(SQC * n, 1.0f - 1e-5f);
    float scale = atanhf(t) / (SQC * n);
    float ox = hv.x * scale, oy = hv.y * scale;
    *reinterpret_cast<float2*>(h_tan + base) = make_float2(ox, oy);
    f16x2 o16 = {(f16)ox, (f16)oy};
    *reinterpret_cast<f16x2*>(h_tan16 + base) = o16;
}

// ---------------------------------------------------------------------------
// CSR build (counting sort by dst), int atomics only
// ---------------------------------------------------------------------------
__global__ __launch_bounds__(256) void hist_kernel(const int* __restrict__ dst,
                                                   int* __restrict__ hist) {
    int t = blockIdx.y;
    int e = blockIdx.x * blockDim.x + threadIdx.x;
    if (e >= E_EDGES) return;
    atomicAdd(&hist[t * N_ENT + dst[(size_t)t * E_EDGES + e]], 1);
}

__global__ __launch_bounds__(1024) void scanA_kernel(const int* __restrict__ hist,
                                                     int* __restrict__ scanned,
                                                     int* __restrict__ partial) {
    __shared__ int s[1024];
    int t = blockIdx.y, blk = blockIdx.x, tid = threadIdx.x;
    int idx = blk * 1024 + tid;
    int v = (idx < N_ENT) ? hist[t * N_ENT + idx] : 0;
    s[tid] = v; __syncthreads();
    #pragma unroll
    for (int off = 1; off < 1024; off <<= 1) {
        int x = (tid >= off) ? s[tid - off] : 0;
        __syncthreads();
        s[tid] += x;
        __syncthreads();
    }
    scanned[t * NPAD + idx] = s[tid];
    if (tid == 1023) partial[t * 40 + blk] = s[1023];
}

__global__ __launch_bounds__(64) void scanB_kernel(int* __restrict__ partial) {
    int t = blockIdx.x, tid = threadIdx.x;
    int orig = (tid < 40) ? partial[t * 40 + tid] : 0;
    int v = orig;
    #pragma unroll
    for (int off = 1; off < 64; off <<= 1) {
        int x = __shfl_up(v, off, 64);
        if (tid >= off) v += x;
    }
    if (tid < 40) partial[t * 40 + tid] = v - orig;   // exclusive
}

__global__ __launch_bounds__(1024) void scanC_kernel(const int* __restrict__ hist,
                                                     const int* __restrict__ scanned,
                                                     const int* __restrict__ partial,
                                                     int* __restrict__ row_ptr,
                                                     int* __restrict__ cursor) {
    int t = blockIdx.y, blk = blockIdx.x, tid = threadIdx.x;
    int idx = blk * 1024 + tid;
    if (idx >= N_ENT) return;
    int incl = scanned[t * NPAD + idx] + partial[t * 40 + blk];
    row_ptr[t * (N_ENT + 1) + idx + 1] = incl;
    cursor[t * N_ENT + idx] = incl - hist[t * N_ENT + idx];
    if (idx == 0) row_ptr[t * (N_ENT + 1)] = 0;
}

// pack (src, rel) into one 32-bit word: src < 2^16, rel < 2^9
__global__ __launch_bounds__(256) void scatter_kernel(const int* __restrict__ src,
                                                      const int* __restrict__ dst,
                                                      const int* __restrict__ rel,
                                                      int* __restrict__ cursor,
                                                      unsigned* __restrict__ sorted) {
    int t = blockIdx.y;
    int e = blockIdx.x * blockDim.x + threadIdx.x;
    if (e >= E_EDGES) return;
    size_t o = (size_t)t * E_EDGES + e;
    int d = dst[o];
    int pos = atomicAdd(&cursor[t * N_ENT + d], 1);
    sorted[(size_t)t * E_EDGES + pos] = (unsigned)src[o] | ((unsigned)rel[o] << 16);
}

// ---------------------------------------------------------------------------
// Gather-mean IN TANGENT SPACE (linearity: mean(ht[s]@wn + er[r]@wn) ==
// mean(ht[s]+er[r]) @ wn). Wave per node, 4 edges/iter, f16x8 loads.
// M16[d] = (sum_{e->d} h_tan16[s_e] + emb_rel16[r_e]) / max(cnt,1)
// ---------------------------------------------------------------------------
__global__ __launch_bounds__(256) void gather_sum_kernel(
        const f16* __restrict__ h_tan16, const f16* __restrict__ emb_rel16,
        const int* __restrict__ row_ptr, const unsigned* __restrict__ sorted,
        f16* __restrict__ M16) {
    int wid  = (blockIdx.x * blockDim.x + threadIdx.x) >> 6;
    int lane = threadIdx.x & 63;
    if (wid >= N_ENT) return;

    const int cb8 = (lane & 15) * 8;
    int beg = row_ptr[wid], end = row_ptr[wid + 1];

    float acc[8];
    #pragma unroll
    for (int j = 0; j < 8; ++j) acc[j] = 0.f;

    for (int e = beg; e < end; e += 4) {
        int idx = e + (lane >> 4);
        bool valid = idx < end;
        unsigned v = sorted[valid ? idx : beg];
        int s = v & 0xFFFFu, r = v >> 16;
        const f16x8 hv = *reinterpret_cast<const f16x8*>(h_tan16  + s * D + cb8);
        const f16x8 rv = *reinterpret_cast<const f16x8*>(emb_rel16 + r * D + cb8);
        float m = valid ? 1.f : 0.f;
        #pragma unroll
        for (int j = 0; j < 8; ++j)
            acc[j] = fmaf(m, (float)hv[j] + (float)rv[j], acc[j]);
    }
    #pragma unroll
    for (int j = 0; j < 8; ++j) {
        acc[j] += __shfl_xor(acc[j], 16, 64);
        acc[j] += __shfl_xor(acc[j], 32, 64);
    }

    if (lane < 16) {
        float inv = 1.0f / fmaxf((float)(end - beg), 1.0f);
        f16x8 o;
        #pragma unroll
        for (int j = 0; j < 8; ++j) o[j] = (f16)(acc[j] * inv);
        *reinterpret_cast<f16x8*>(M16 + (size_t)wid * D + cb8) = o;
    }
}

// ---------------------------------------------------------------------------
// Fused GEMM + mix: per 64-row block stage M16 and h_tan16 tiles in LDS,
// compute P = M@wn, L = ht@wl, G = ht@wg via MFMA (register-resident),
// then in the epilogue: o = rrelu(P + L); g = sigmoid(G);
// mixed = g*o + (1-g)*ht32.  !last: write h_tan(+16); last: h_out=expmap0(mixed).
// ---------------------------------------------------------------------------
__global__ __launch_bounds__(256) void gemm_mix_kernel(
        const f16* __restrict__ M16, f16* __restrict__ h_tan16,
        float* __restrict__ h_tan, const f16* __restrict__ wpack,
        float* __restrict__ h_out, int last) {
    __shared__ f16 m_s[64 * 128];
    __shared__ f16 a_s[64 * 128];
    const int tid = threadIdx.x;
    const int rowBase = blockIdx.x * 64;

    {   // stage both tiles, XOR-swizzled (half-index ^ ((row&7)<<3))
        int r = tid >> 2, q = tid & 3;
        const float4* srcM = reinterpret_cast<const float4*>(M16     + (size_t)(rowBase + r) * D + q * 32);
        const float4* srcA = reinterpret_cast<const float4*>(h_tan16 + (size_t)(rowBase + r) * D + q * 32);
        #pragma unroll
        for (int i = 0; i < 4; ++i) {
            int hoff = (q * 32 + i * 8) ^ ((r & 7) << 3);
            *reinterpret_cast<float4*>(&m_s[r * 128 + hoff]) = srcM[i];
            *reinterpret_cast<float4*>(&a_s[r * 128 + hoff]) = srcA[i];
        }
    }
    __syncthreads();

    const int wave = tid >> 6, lane = tid & 63;
    const int arow = wave * 16 + (lane & 15);

    f16x8 afM[4], afH[4];
    #pragma unroll
    for (int ks = 0; ks < 4; ++ks) {
        int hoff = (ks * 32 + (lane >> 4) * 8) ^ ((arow & 7) << 3);
        afM[ks] = *reinterpret_cast<const f16x8*>(&m_s[arow * 128 + hoff]);
        afH[ks] = *reinterpret_cast<const f16x8*>(&a_s[arow * 128 + hoff]);
    }

    const int orow = rowBase + arow;
    const int colq = (lane >> 4) * 4;

    f32x4 mx[8];
    float ss = 0.f;

    #pragma unroll
    for (int nt = 0; nt < 8; ++nt) {
        f32x4 accP = {0.f, 0.f, 0.f, 0.f};
        f32x4 accL = {0.f, 0.f, 0.f, 0.f};
        f32x4 accG = {0.f, 0.f, 0.f, 0.f};
        #pragma unroll
        for (int ks = 0; ks < 4; ++ks) {
            const f16x8 wfN = *reinterpret_cast<const f16x8*>(wpack + ((((0 * 8 + nt) * 4 + ks) * 64 + lane) << 3));
            const f16x8 wfL = *reinterpret_cast<const f16x8*>(wpack + ((((1 * 8 + nt) * 4 + ks) * 64 + lane) << 3));
            const f16x8 wfG = *reinterpret_cast<const f16x8*>(wpack + ((((2 * 8 + nt) * 4 + ks) * 64 + lane) << 3));
            accP = __builtin_amdgcn_mfma_f32_16x16x32_f16(wfN, afM[ks], accP, 0, 0, 0);
            accL = __builtin_amdgcn_mfma_f32_16x16x32_f16(wfL, afH[ks], accL, 0, 0, 0);
            accG = __builtin_amdgcn_mfma_f32_16x16x32_f16(wfG, afH[ks], accG, 0, 0, 0);
        }
        const size_t cidx = (size_t)orow * D + nt * 16 + colq;
        f32x4 ht = *reinterpret_cast<const f32x4*>(h_tan + cidx);
        f32x4 m;
        #pragma unroll
        for (int i = 0; i < 4; ++i) {
            float o = accP[i] + accL[i];
            o = (o >= 0.f) ? o : RRELU_SLOPE * o;
            float g = 1.0f / (1.0f + expf(-accG[i]));
            m[i] = fmaf(g, o - ht[i], ht[i]);
            ss = fmaf(m[i], m[i], ss);
        }
        mx[nt] = m;
        if (!last) {
            *reinterpret_cast<f32x4*>(h_tan + cidx) = m;
            f16x4 m16 = {(f16)m[0], (f16)m[1], (f16)m[2], (f16)m[3]};
            *reinterpret_cast<f16x4*>(h_tan16 + cidx) = m16;
        }
    }

    if (last) {
        // row-norm across the 4 colq groups (lanes differing in bits 4,5)
        ss += __shfl_xor(ss, 16, 64);
        ss += __shfl_xor(ss, 32, 64);
        float n = fmaxf(sqrtf(ss), EPS_);
        float s = tanhf(SQC * n) / (SQC * n);
        #pragma unroll
        for (int nt = 0; nt < 8; ++nt) {
            const size_t cidx = (size_t)orow * D + nt * 16 + colq;
            f32x4 o = {mx[nt][0] * s, mx[nt][1] * s, mx[nt][2] * s, mx[nt][3] * s};
            *reinterpret_cast<f32x4*>(h_out + cidx) = o;
        }
    }
}

// ---------------------------------------------------------------------------
extern "C" void kernel_launch(void* const* d_in, const int* in_sizes, int n_in,
                              void* d_out, int out_size, void* d_ws, size_t ws_size,
                              hipStream_t stream) {
    const int*   src  = (const int*)d_in[0];
    const int*   dst  = (const int*)d_in[1];
    const int*   rel  = (const int*)d_in[2];
    const float* dyn  = (const float*)d_in[3];
    const float* erel = (const float*)d_in[4];
    const float* wn   = (const float*)d_in[5];
    const float* wl   = (const float*)d_in[6];
    const float* wg   = (const float*)d_in[7];
    float* h = (float*)d_out;

    const size_t ND = (size_t)N_ENT * D;
    char* p = (char*)d_ws;
    float* h_tan    = (float*)p;            p += ND * 4;
    f16*   h_tan16  = (f16*)p;              p += ND * 2;
    f16*   M16      = (f16*)p;              p += ND * 2;
    f16*   emb_rel16= (f16*)p;              p += (size_t)N_REL2 * D * 2;
    f16*   wpack    = (f16*)p;              p += (size_t)3 * D * D * 2;
    unsigned* sorted= (unsigned*)p;         p += (size_t)T_STEPS * E_EDGES * 4;
    int*   hist     = (int*)p;              p += (size_t)T_STEPS * N_ENT * 4;
    int*   scanned  = (int*)p;              p += (size_t)T_STEPS * NPAD * 4;
    int*   partial  = (int*)p;              p += (size_t)T_STEPS * 64 * 4;
    int*   row_ptr  = (int*)p;              p += (size_t)T_STEPS * (N_ENT + 1) * 4;
    int*   cursor   = (int*)p;

    const int nodeBlocks = (N_ENT * 64 + 255) / 256;           // 10000
    const int edgeB      = (E_EDGES + 255) / 256;              // 782

    // CSR build (all 8 steps)
    hipMemsetAsync(hist, 0, (size_t)T_STEPS * N_ENT * sizeof(int), stream);
    hist_kernel<<<dim3(edgeB, T_STEPS), 256, 0, stream>>>(dst, hist);
    scanA_kernel<<<dim3(40, T_STEPS), 1024, 0, stream>>>(hist, scanned, partial);
    scanB_kernel<<<T_STEPS, 64, 0, stream>>>(partial);
    scanC_kernel<<<dim3(40, T_STEPS), 1024, 0, stream>>>(hist, scanned, partial, row_ptr, cursor);
    scatter_kernel<<<dim3(edgeB, T_STEPS), 256, 0, stream>>>(src, dst, rel, cursor, sorted);

    // loop-invariant precompute
    cvt_rel_kernel<<<(N_REL2 * D + 255) / 256, 256, 0, stream>>>(erel, emb_rel16);
    cvtw_kernel<<<192, 256, 0, stream>>>(wn, wl, wg, wpack);
    logmap_kernel<<<nodeBlocks, 256, 0, stream>>>(dyn, h_tan, h_tan16);

    for (int t = 0; t < T_STEPS; ++t) {
        gather_sum_kernel<<<nodeBlocks, 256, 0, stream>>>(
            h_tan16, emb_rel16,
            row_ptr + t * (N_ENT + 1), sorted + (size_t)t * E_EDGES, M16);
        gemm_mix_kernel<<<N_ENT / 64, 256, 0, stream>>>(
            M16, h_tan16, h_tan, wpack, h, (t == T_STEPS - 1) ? 1 : 0);
    }
}